// Round 1
// baseline (1580.701 us; speedup 1.0000x reference)
//
#include <hip/hip_runtime.h>
#include <hip/hip_bf16.h>

#define T_ 1024
#define B_ 64
#define H_ 128
#define G_ 512   // 4*H
#define E_ 128
#define V_ 32
#define N_ 8

// ---------------------------------------------------------------------------
// K0: proj[dir][v][g] = b_dir[g] + sum_e W_ih_dir[g][e] * emb[v][e]
// grid 64 = dir*32+v, block 512 (one thread per g)
// ---------------------------------------------------------------------------
__global__ __launch_bounds__(512) void proj_kernel(
    const float* __restrict__ emb,
    const float* __restrict__ Wih_f, const float* __restrict__ b_f,
    const float* __restrict__ Wih_b, const float* __restrict__ b_b,
    float* __restrict__ proj)
{
    int wg  = blockIdx.x;
    int dir = wg >> 5;
    int v   = wg & 31;
    const float* W    = dir ? Wih_b : Wih_f;
    const float* bias = dir ? b_b   : b_f;
    int tid = threadIdx.x;

    __shared__ float4 e_l[E_ / 4];
    if (tid < E_ / 4) e_l[tid] = ((const float4*)(emb + (size_t)v * E_))[tid];
    __syncthreads();

    float acc = bias[tid];
    const float4* wr = (const float4*)(W + (size_t)tid * E_);
#pragma unroll
    for (int k = 0; k < 32; ++k) {
        float4 wv = wr[k], ev = e_l[k];
        acc += wv.x * ev.x;
        acc += wv.y * ev.y;
        acc += wv.z * ev.z;
        acc += wv.w * ev.w;
    }
    proj[((size_t)dir * V_ + v) * G_ + tid] = acc;
}

// ---------------------------------------------------------------------------
// K1: per-(dir,batch) LSTM chain + fused FC partials.
// grid 128 (dir*64+b), block 512. Thread i owns W_hh row i in 128 VGPRs.
// part[dir][t][b][n] = sum_j fc_W[n][dir*128+j] * h_dir[t][b][j]
// ---------------------------------------------------------------------------
__global__ __launch_bounds__(512, 2) void lstm_kernel(
    const int*   __restrict__ x,
    const float* __restrict__ Whh_f, const float* __restrict__ Whh_b,
    const float* __restrict__ proj,   // [2][V][G]
    const float* __restrict__ fcW,    // [8][256]
    float* __restrict__ part)         // [2][T][B][8]
{
    int wg  = blockIdx.x;
    int dir = wg >> 6;
    int b   = wg & 63;
    int tid = threadIdx.x;

    __shared__ int    tok_l[T_];
    __shared__ float  g_l[G_];
    __shared__ float4 h_l4[H_ / 4];
    __shared__ float  fcw_l[N_][H_];
    float* h_l = (float*)h_l4;

    for (int q = tid; q < T_; q += 512) tok_l[q] = x[(size_t)b * T_ + q];
    for (int q = tid; q < N_ * H_; q += 512) {
        int n = q >> 7, j = q & 127;
        fcw_l[n][j] = fcW[n * 256 + dir * H_ + j];
    }
    if (tid < H_) h_l[tid] = 0.f;

    const float* Whh = dir ? Whh_b : Whh_f;
    float4 wv[32];
    const float4* wrow = (const float4*)(Whh + (size_t)tid * H_);
#pragma unroll
    for (int k = 0; k < 32; ++k) wv[k] = wrow[k];

    const float* projd = proj + (size_t)dir * (V_ * G_);
    int sel = tid >> 7;  // 0:i-gate 1:f-gate 2:g(tanh) 3:o-gate  (wave-uniform)
    float c = 0.f;
    __syncthreads();

    for (int t = 0; t < T_; ++t) {
        int tt  = dir ? (T_ - 1 - t) : t;
        int tok = tok_l[tt];
        float pv = projd[tok * G_ + tid];  // issued early, consumed after matvec

        float acc = 0.f;
#pragma unroll
        for (int k = 0; k < 32; ++k) {
            float4 hv = h_l4[k];
            acc += wv[k].x * hv.x;
            acc += wv[k].y * hv.y;
            acc += wv[k].z * hv.z;
            acc += wv[k].w * hv.w;
        }
        float g = acc + pv;
        // apply own activation (spreads transcendentals over all 8 waves)
        float a = (sel == 2) ? tanhf(g) : 1.f / (1.f + expf(-g));
        g_l[tid] = a;
        __syncthreads();

        if (tid < H_) {
            float si = g_l[tid];
            float sf = g_l[tid + 128];
            float tg = g_l[tid + 256];
            float so = g_l[tid + 384];
            c = sf * c + si * tg;
            float h = so * tanhf(c);
            h_l[tid] = h;
        }
        __syncthreads();

        // fused FC partial: runs on waves 0-1, overlaps next step's matvec
        if (tid < H_) {
            int n = tid >> 4, m = tid & 15;
            float p = 0.f;
#pragma unroll
            for (int q = 0; q < 8; ++q) p += fcw_l[n][m + 16 * q] * h_l[m + 16 * q];
            p += __shfl_xor(p, 1);
            p += __shfl_xor(p, 2);
            p += __shfl_xor(p, 4);
            p += __shfl_xor(p, 8);
            if (m == 0) part[(((size_t)dir * T_ + tt) * B_ + b) * N_ + n] = p;
        }
    }
}

// ---------------------------------------------------------------------------
// K2: Viterbi forward + backtrack. grid 64 (one wave per batch element).
// lane = i*8+j. Invariant: every lane's `score` = score[lane&7].
// ---------------------------------------------------------------------------
__global__ __launch_bounds__(64) void viterbi_kernel(
    const float* __restrict__ part,   // [2][T][B][8]
    const float* __restrict__ fc_b,
    const float* __restrict__ start_t,
    const float* __restrict__ end_t,
    const float* __restrict__ trans,  // [8][8]
    int* __restrict__ out)            // [B][T]
{
    int b = blockIdx.x;
    int l = threadIdx.x;
    int i_of = l >> 3, j_of = l & 7;

    __shared__ float        em_l[64][N_];
    __shared__ unsigned int hist_l[T_];

    float tr  = trans[l];        // trans[i_of][j_of]
    float fcb = fc_b[j_of];
    const float* pf = part;
    const float* pb = part + (size_t)T_ * B_ * N_;

    float score = 0.f;

    for (int t0 = 0; t0 < T_; t0 += 64) {
        // stage 64 steps of emissions: em = (pf + pb) + fcb
#pragma unroll
        for (int pass = 0; pass < 8; ++pass) {
            int t = t0 + pass * 8 + i_of;
            size_t base = ((size_t)t * B_ + b) * N_ + j_of;
            em_l[pass * 8 + i_of][j_of] = (pf[base] + pb[base]) + fcb;
        }
        __syncthreads();

        int qstart = 0;
        if (t0 == 0) {
            score  = start_t[j_of] + em_l[0][j_of];
            qstart = 1;
        }
        for (int q = qstart; q < 64; ++q) {
            int t = t0 + q;
            float em  = em_l[q][j_of];
            float s_i = __shfl(score, i_of);     // score[i]
            float v   = (s_i + tr) + em;         // match ref add order
            int   idx = i_of;
#pragma unroll
            for (int d = 8; d <= 32; d <<= 1) {  // argmax over i, first-index ties
                float ov = __shfl_xor(v, d);
                int   oi = __shfl_xor(idx, d);
                if (ov > v || (ov == v && oi < idx)) { v = ov; idx = oi; }
            }
            score = v;
            unsigned int pk = (unsigned int)idx << (3 * j_of);
            pk |= __shfl_xor(pk, 1);
            pk |= __shfl_xor(pk, 2);
            pk |= __shfl_xor(pk, 4);
            if (l == 0) hist_l[t] = pk;
        }
        __syncthreads();
    }

    // finalize: score += end_trans; last_tag = argmax_j (first-index ties)
    score += end_t[j_of];
    float v = score;
    int   idx = j_of;
#pragma unroll
    for (int d = 1; d <= 4; d <<= 1) {
        float ov = __shfl_xor(v, d);
        int   oi = __shfl_xor(idx, d);
        if (ov > v || (ov == v && oi < idx)) { v = ov; idx = oi; }
    }
    int tag = idx;
    if (l == 0) out[(size_t)b * T_ + (T_ - 1)] = tag;
    __syncthreads();

    // backtrack: prefetch 16 packed words per block -> serial chain is VALU-only
    for (int t0b = T_ - 16; t0b >= 0; t0b -= 16) {
        unsigned int pk[16];
#pragma unroll
        for (int q = 0; q < 16; ++q) pk[q] = hist_l[t0b + q];
#pragma unroll
        for (int q = 15; q >= 0; --q) {
            int t = t0b + q;
            if (t >= 1) {
                tag = (pk[q] >> (3 * tag)) & 7;
                if (l == 0) out[(size_t)b * T_ + t - 1] = tag;
            }
        }
    }
}

extern "C" void kernel_launch(void* const* d_in, const int* in_sizes, int n_in,
                              void* d_out, int out_size, void* d_ws, size_t ws_size,
                              hipStream_t stream) {
    (void)in_sizes; (void)n_in; (void)out_size; (void)ws_size;
    const int*   x      = (const int*)  d_in[0];
    const float* emb    = (const float*)d_in[1];
    const float* Wih_f  = (const float*)d_in[2];
    const float* Whh_f  = (const float*)d_in[3];
    const float* b_f    = (const float*)d_in[4];
    const float* Wih_b  = (const float*)d_in[5];
    const float* Whh_b  = (const float*)d_in[6];
    const float* b_b    = (const float*)d_in[7];
    const float* fcW    = (const float*)d_in[8];
    const float* fcb    = (const float*)d_in[9];
    const float* startt = (const float*)d_in[10];
    const float* endt   = (const float*)d_in[11];
    const float* trans  = (const float*)d_in[12];

    float* proj = (float*)d_ws;                    // 2*32*512 floats = 128 KB
    float* part = proj + 2 * V_ * G_;              // 2*1024*64*8 floats = 4 MB
    int*   out  = (int*)d_out;

    proj_kernel<<<64, 512, 0, stream>>>(emb, Wih_f, b_f, Wih_b, b_b, proj);
    lstm_kernel<<<128, 512, 0, stream>>>(x, Whh_f, Whh_b, proj, fcW, part);
    viterbi_kernel<<<64, 64, 0, stream>>>(part, fcb, startt, endt, trans, out);
}